// Round 7
// baseline (197.599 us; speedup 1.0000x reference)
//
#include <hip/hip_runtime.h>
#include <math.h>

static constexpr int BROWS   = 16384;
static constexpr int NC      = 784;
static constexpr int TRB     = 16;              // rows per tile/block
static constexpr int THREADS = 256;             // 4 waves; 784 cols = 3*256+16 -> 94% wave balance
static constexpr int NBLK    = BROWS / TRB;     // 1024 blocks
static constexpr int NSLOT   = 4;               // ceil(784/256) column slots per thread
static constexpr int NREP    = 4;               // replicated stat accumulators
static constexpr float EPS   = 1e-5f;
static constexpr float INV_B = 1.0f / (float)BROWS;

#if defined(__has_builtin)
#if __has_builtin(__builtin_amdgcn_global_load_lds)
#define HAVE_ASYNC_LDS 1
#endif
#if __has_builtin(__builtin_amdgcn_rcpf)
#define HAVE_RCPF 1
#endif
#if __has_builtin(__builtin_elementwise_fma)
#define HAVE_EW_FMA 1
#endif
#endif

typedef float v2f __attribute__((ext_vector_type(2)));

__device__ __forceinline__ void stage16(const float4* g, float4* l) {
#ifdef HAVE_ASYNC_LDS
    __builtin_amdgcn_global_load_lds(
        (const __attribute__((address_space(1))) void*)g,
        (__attribute__((address_space(3))) void*)l, 16, 0, 0);
#else
    *l = *g;
#endif
}

// ---- bf16 helpers (raw u16 storage; RNE convert) ----
__device__ __forceinline__ unsigned short f2b(float f) {
    union { float f; unsigned u; } v; v.f = f;
    const unsigned r = v.u + 0x7fffu + ((v.u >> 16) & 1u);
    return (unsigned short)(r >> 16);
}
__device__ __forceinline__ unsigned pack2(float lo, float hi) {
    return (unsigned)f2b(lo) | ((unsigned)f2b(hi) << 16);
}
__device__ __forceinline__ unsigned long long pack4(float a, float b, float c, float d) {
    return (unsigned long long)pack2(a, b) | ((unsigned long long)pack2(c, d) << 32);
}
__device__ __forceinline__ float fast_rcp(float x) {
#ifdef HAVE_RCPF
    return __builtin_amdgcn_rcpf(x);
#else
    return 1.0f / x;
#endif
}

// tanh-form gelu (max |err| ~3e-4, far under the 0.2625 budget), branchless.
__device__ __forceinline__ float gelu_f(float x) {
    const float u  = x * x;
    const float z  = x * fmaf(0.0356774081f, u, 0.7978845608f);
    const float e  = __expf(2.0f * z);            // e^{2z}
    const float r  = fast_rcp(e + 1.0f);
    const float t  = fmaf(-2.0f, r, 1.0f);        // tanh(z)
    const float hx = 0.5f * x;
    return fmaf(hx, t, hx);
}

// u64 = 4 bf16 rows of one column (rows 4q..4q+3). Unpack to 2x v2f and FMA
// with packed v_pk_fma_f32.
__device__ __forceinline__ void fmaq(const unsigned long long v, const float w, v2f acc[2]) {
    const unsigned lo = (unsigned)v, hi = (unsigned)(v >> 32);
    union { unsigned u; float f; } a0, a1, b0, b1;
    a0.u = lo << 16; a1.u = lo & 0xffff0000u;
    b0.u = hi << 16; b1.u = hi & 0xffff0000u;
    const v2f a = { a0.f, a1.f }, b = { b0.f, b1.f };
    const v2f w2 = { w, w };
#ifdef HAVE_EW_FMA
    acc[0] = __builtin_elementwise_fma(a, w2, acc[0]);
    acc[1] = __builtin_elementwise_fma(b, w2, acc[1]);
#else
    acc[0] += a * w2;
    acc[1] += b * w2;
#endif
}

// Batch-gather: issue ALL CH*4 ds_read_b64 into registers first, THEN the FMA
// block. One lgkmcnt wait per chunk instead of per-read dependency stalls.
template<int CH>
__device__ __forceinline__ void gchunk(const unsigned long long* __restrict__ tile,
                                       const int* ji, const float* jw,
                                       v2f acc[4][2])
{
    unsigned long long t[CH][4];
    #pragma unroll
    for (int k = 0; k < CH; ++k) {
        #pragma unroll
        for (int q = 0; q < 4; ++q) t[k][q] = tile[q * NC + ji[k]];
    }
    #pragma unroll
    for (int k = 0; k < CH; ++k) {
        #pragma unroll
        for (int q = 0; q < 4; ++q) fmaq(t[k][q], jw[k], acc[q]);
    }
}

template<int K>
__device__ __forceinline__ void gacc(const unsigned long long* __restrict__ tile,
                                     const int* ji, const float* jw, const float jb,
                                     v2f acc[4][2])
{
    #pragma unroll
    for (int q = 0; q < 4; ++q) { acc[q][0] = (v2f){ jb, jb }; acc[q][1] = (v2f){ jb, jb }; }
    if (K == 8) {
        gchunk<4>(tile, ji,     jw,     acc);
        gchunk<4>(tile, ji + 4, jw + 4, acc);
    } else {
        gchunk<K>(tile, ji, jw, acc);
    }
}

// ---------------- K_A: fused L1 -> gelu -> L2 -> gelu (+ bn2a stats) ----------------
// Single 25 KB tile, in-place: L1 outputs are computed fully into registers,
// then written back after a barrier (WAR-safe). 5 blocks/CU, no tail round.
__global__ __launch_bounds__(THREADS, 5)
void k12(const float* __restrict__ x,
         const int* __restrict__ idx1, const float* __restrict__ W1, const float* __restrict__ b1,
         const int* __restrict__ idx2, const float* __restrict__ W2, const float* __restrict__ b2,
         unsigned long long* __restrict__ outr,
         float* __restrict__ ssum, float* __restrict__ ssq)
{
    __shared__ unsigned long long tile[4 * NC];    // 25088 B
    const int tid  = threadIdx.x;
    const int row0 = blockIdx.x * TRB;

    // stage x (fp32 row-major) -> quad bf16 tile (coalesced dword reads per row)
    #pragma unroll
    for (int s = 0; s < NSLOT; ++s) {
        const int c = tid + s * THREADS;
        if (c < NC) {
            #pragma unroll
            for (int q = 0; q < 4; ++q) {
                const size_t base = (size_t)(row0 + 4 * q) * NC + c;
                tile[q * NC + c] = pack4(x[base], x[base + NC], x[base + 2 * NC], x[base + 3 * NC]);
            }
        }
    }
    __syncthreads();

    // L1 (K=2): compute ALL slots into registers (tile only read here)
    unsigned long long o[NSLOT][4];
    #pragma unroll
    for (int s = 0; s < NSLOT; ++s) {
        const int j = tid + s * THREADS;
        if (j < NC) {
            int ji[2]; float jw[2];
            ji[0] = idx1[2 * j]; ji[1] = idx1[2 * j + 1];
            jw[0] = W1[2 * j];   jw[1] = W1[2 * j + 1];
            v2f acc[4][2];
            gacc<2>(tile, ji, jw, b1[j], acc);
            #pragma unroll
            for (int q = 0; q < 4; ++q)
                o[s][q] = pack4(gelu_f(acc[q][0].x), gelu_f(acc[q][0].y),
                                gelu_f(acc[q][1].x), gelu_f(acc[q][1].y));
        }
    }
    __syncthreads();                               // all L1 reads done
    #pragma unroll
    for (int s = 0; s < NSLOT; ++s) {
        const int j = tid + s * THREADS;
        if (j < NC) {
            #pragma unroll
            for (int q = 0; q < 4; ++q) tile[q * NC + j] = o[s][q];
        }
    }
    __syncthreads();

    // L2 (K=4) + gelu + stats + quad global store
    const int rep = blockIdx.x & (NREP - 1);
    unsigned long long* dst = outr + (size_t)blockIdx.x * 4 * NC;
    #pragma unroll
    for (int s = 0; s < NSLOT; ++s) {
        const int j = tid + s * THREADS;
        if (j < NC) {
            int ji[4]; float jw[4];
            #pragma unroll
            for (int k = 0; k < 4; ++k) { ji[k] = idx2[4 * j + k]; jw[k] = W2[4 * j + k]; }
            v2f acc[4][2];
            gacc<4>(tile, ji, jw, b2[j], acc);
            float s1 = 0.0f, s2 = 0.0f;
            #pragma unroll
            for (int q = 0; q < 4; ++q) {
                const float u0 = gelu_f(acc[q][0].x), u1 = gelu_f(acc[q][0].y);
                const float u2 = gelu_f(acc[q][1].x), u3 = gelu_f(acc[q][1].y);
                s1 += (u0 + u1) + (u2 + u3);
                s2 = fmaf(u0, u0, fmaf(u1, u1, fmaf(u2, u2, fmaf(u3, u3, s2))));
                dst[q * NC + j] = pack4(u0, u1, u2, u3);
            }
            atomicAdd(&ssum[rep * NC + j], s1);
            atomicAdd(&ssq[rep * NC + j],  s2);
        }
    }
}

// -------- K_B/C/D: fold prev BN into weights -> sparse -> act (+ stats) --------
template<int K, bool FINAL>
__global__ __launch_bounds__(THREADS, 5)    // 5 blocks/CU: no tail, VGPR cap ~96
void kbn(const unsigned long long* __restrict__ inr,
         const int* __restrict__ idx, const float* __restrict__ W, const float* __restrict__ bias,
         const float* __restrict__ gamma, const float* __restrict__ beta,
         const float* __restrict__ psum, const float* __restrict__ psq,
         unsigned long long* __restrict__ outr, float* __restrict__ fout,
         float* __restrict__ ssum, float* __restrict__ ssq)
{
    __shared__ unsigned long long tile[4 * NC];    // 25088 B
    __shared__ float s_sc[NC], s_sh[NC];           //  6272 B
    const int tid  = threadIdx.x;
    const int row0 = blockIdx.x * TRB;

    {   // async DMA of the contiguous quad region (lane-linear dst)
        const float4* src = (const float4*)(inr + (size_t)blockIdx.x * 4 * NC);
        float4*       dstl = (float4*)tile;
        for (int i = tid; i < 4 * NC / 2; i += THREADS) stage16(src + i, dstl + i);
    }
    // finalize previous BN into scale/shift (L2-hot; overlaps the DMA)
    for (int j = tid; j < NC; j += THREADS) {
        float s1 = 0.0f, s2 = 0.0f;
        #pragma unroll
        for (int r = 0; r < NREP; ++r) { s1 += psum[r * NC + j]; s2 += psq[r * NC + j]; }
        const float m   = s1 * INV_B;
        const float var = fmaf(-m, m, s2 * INV_B);
        const float sc  = gamma[j] * rsqrtf(var + EPS);
        s_sc[j] = sc;
        s_sh[j] = fmaf(-m, sc, beta[j]);
    }
    __syncthreads();   // drains DMA + publishes sc/sh

    const int rep = blockIdx.x & (NREP - 1);
    unsigned long long* dst = FINAL ? nullptr : (outr + (size_t)blockIdx.x * 4 * NC);
    #pragma unroll
    for (int s = 0; s < NSLOT; ++s) {
        const int j = tid + s * THREADS;
        if (j < NC) {
            int ji[K]; float jw[K];
            float jb = bias[j];
            #pragma unroll
            for (int k = 0; k < K; ++k) {
                const int   c = idx[K * j + k];
                const float w = W[K * j + k];
                ji[k] = c; jw[k] = w * s_sc[c]; jb = fmaf(w, s_sh[c], jb);
            }
            v2f acc[4][2];
            gacc<K>(tile, ji, jw, jb, acc);
            if (FINAL) {
                #pragma unroll
                for (int q = 0; q < 4; ++q) {
                    fout[(size_t)(row0 + 4 * q + 0) * NC + j] = fmaxf(acc[q][0].x, 0.0f);
                    fout[(size_t)(row0 + 4 * q + 1) * NC + j] = fmaxf(acc[q][0].y, 0.0f);
                    fout[(size_t)(row0 + 4 * q + 2) * NC + j] = fmaxf(acc[q][1].x, 0.0f);
                    fout[(size_t)(row0 + 4 * q + 3) * NC + j] = fmaxf(acc[q][1].y, 0.0f);
                }
            } else {
                float s1 = 0.0f, s2 = 0.0f;
                #pragma unroll
                for (int q = 0; q < 4; ++q) {
                    const float u0 = gelu_f(acc[q][0].x), u1 = gelu_f(acc[q][0].y);
                    const float u2 = gelu_f(acc[q][1].x), u3 = gelu_f(acc[q][1].y);
                    s1 += (u0 + u1) + (u2 + u3);
                    s2 = fmaf(u0, u0, fmaf(u1, u1, fmaf(u2, u2, fmaf(u3, u3, s2))));
                    dst[q * NC + j] = pack4(u0, u1, u2, u3);
                }
                atomicAdd(&ssum[rep * NC + j], s1);
                atomicAdd(&ssq[rep * NC + j],  s2);
            }
        }
    }
}

extern "C" void kernel_launch(void* const* d_in, const int* in_sizes, int n_in,
                              void* d_out, int out_size, void* d_ws, size_t ws_size,
                              hipStream_t stream)
{
    const float* x    = (const float*)d_in[0];
    const int*   idx1 = (const int*)  d_in[1];
    const float* W1   = (const float*)d_in[2];
    const float* b1   = (const float*)d_in[3];
    const int*   idx2 = (const int*)  d_in[4];
    const float* W2   = (const float*)d_in[5];
    const float* b2   = (const float*)d_in[6];
    const int*   idx3 = (const int*)  d_in[7];
    const float* W3   = (const float*)d_in[8];
    const float* b3   = (const float*)d_in[9];
    const float* g2   = (const float*)d_in[10];
    const float* be2  = (const float*)d_in[11];
    const float* g3   = (const float*)d_in[12];
    const float* be3  = (const float*)d_in[13];
    float* out = (float*)d_out;

    const size_t QN = (size_t)NBLK * 4 * NC;       // u64 elems per intermediate
    // Quad-layout bf16 ping-pong:
    //   k12      : r x  -> w r0
    //   kbn<8>   : r r0 -> w r1
    //   kbn<4>   : r r1 -> w r0
    //   kbn<2,F> : r r0 -> w out (fp32 row-major)
    unsigned long long* r0 = (unsigned long long*)d_ws;
    unsigned long long* r1 = r0 + QN;
    float* p = (float*)(r1 + QN);
    float* sum2a = p; p += NREP * NC;  float* ssq2a = p; p += NREP * NC;
    float* sum3  = p; p += NREP * NC;  float* ssq3  = p; p += NREP * NC;
    float* sum2b = p; p += NREP * NC;  float* ssq2b = p; p += NREP * NC;

    hipMemsetAsync(sum2a, 0, 6 * NREP * NC * sizeof(float), stream);

    const dim3 grid(NBLK), blk(THREADS);

    k12<<<grid, blk, 0, stream>>>(x, idx1, W1, b1, idx2, W2, b2, r0, sum2a, ssq2a);
    kbn<8, false><<<grid, blk, 0, stream>>>(
        r0, idx3, W3, b3, g2, be2, sum2a, ssq2a, r1, nullptr, sum3, ssq3);
    kbn<4, false><<<grid, blk, 0, stream>>>(
        r1, idx2, W2, b2, g3, be3, sum3, ssq3, r0, nullptr, sum2b, ssq2b);
    kbn<2, true><<<grid, blk, 0, stream>>>(
        r0, idx1, W1, b1, g2, be2, sum2b, ssq2b, nullptr, out, nullptr, nullptr);
}